// Round 9
// baseline (4951.107 us; speedup 1.0000x reference)
//
#include <hip/hip_runtime.h>
#include <hip/hip_bf16.h>
#include <cstdint>
#include <cstddef>

#define T_STEPS 1024
#define BATCH   128
#define INF     128   // used input features (130 minus last 2)
#define HID     512
#define NBLK    128   // 32 ug x 4 bg-pairs; each block runs 2 interleaved recurrences
#define NTHR    512   // 8 waves: kq = w&3 (160-deep k quarter), th = w>>2 (2 of 4 gates)
#define PK      648   // padded k stride (bf16 units) in LDS Z planes
#define Z_SHORTS    (2 * 16 * PK)            // 20736 shorts = 41472 B per zpl
#define GSTR        17
#define GATE_FLOATS (4 * 4 * 16 * GSTR)      // 4352 floats = 17408 B
#define SMEM_BYTES  (2 * Z_SHORTS * 2 + GATE_FLOATS * 4)   // 100352 B

typedef short  bf16x8 __attribute__((ext_vector_type(8)));
typedef float  f32x4  __attribute__((ext_vector_type(4)));

static __device__ __forceinline__ unsigned short bf_hi(float v) {
  __hip_bfloat16 h = __float2bfloat16(v);
  return *reinterpret_cast<unsigned short*>(&h);
}
static __device__ __forceinline__ float bf_val(unsigned short u) {
  __hip_bfloat16 h = *reinterpret_cast<__hip_bfloat16*>(&u);
  return __bfloat162float(h);
}
static __device__ __forceinline__ float fsigmoid(float x) {
  return 1.f / (1.f + __expf(-x));
}
static __device__ __forceinline__ float ftanh(float x) {
  return 1.f - 2.f / (__expf(2.f * x) + 1.f);
}

// ---------------- pre-pass kernels (unchanged from round 6) ----------------

// xp[t*8+bg][p][c 16][k 128] bf16 (p=0 hi, p=1 lo)
__global__ __launch_bounds__(256) void k_prep_x(const float* __restrict__ in,
                                                unsigned short* __restrict__ xp)
{
  int t = blockIdx.x >> 3, bg = blockIdx.x & 7;
  int tid = threadIdx.x;
  size_t base = (size_t)blockIdx.x * 4096;
  #pragma unroll
  for (int rep = 0; rep < 8; ++rep) {
    int idx = rep * 256 + tid;           // 0..2047
    int c = idx >> 7, k = idx & 127;
    float v = in[((size_t)(bg * 16 + c) * T_STEPS + t) * 130 + k];
    unsigned short hi = bf_hi(v);
    unsigned short lo = bf_hi(v - bf_val(hi));
    xp[base + c * 128 + k]        = hi;
    xp[base + 2048 + c * 128 + k] = lo;
  }
}

// W A-fragments, bf16 hi/lo, per-lane MFMA layout.
// blk = ((ug*4+q)*4+kq)*5+s   (2560 blocks x 64 threads)
__global__ __launch_bounds__(64) void k_prep_w(const float* __restrict__ Wih,
                                               const float* __restrict__ Whh,
                                               unsigned short* __restrict__ wf)
{
  int blk = blockIdx.x;
  int s = blk % 5; int r = blk / 5;
  int kq = r & 3; int q = (r >> 2) & 3; int ug = r >> 4;
  int l = threadIdx.x;
  int Grow = q * HID + ug * 16 + (l & 15);
  int kb = kq * 160 + s * 32 + (l >> 4) * 8;
  float v[8];
  #pragma unroll
  for (int j = 0; j < 8; ++j)
    v[j] = (kb < INF) ? Wih[(size_t)Grow * INF + kb + j]
                      : Whh[(size_t)Grow * HID + (kb - INF) + j];
  unsigned short hi[8], lo[8];
  #pragma unroll
  for (int j = 0; j < 8; ++j) {
    hi[j] = bf_hi(v[j]);
    lo[j] = bf_hi(v[j] - bf_val(hi[j]));
  }
  unsigned short* dh = wf + ((size_t)(blk * 2 + 0) * 64 + l) * 8;
  unsigned short* dl = wf + ((size_t)(blk * 2 + 1) * 64 + l) * 8;
  #pragma unroll
  for (int j = 0; j < 8; ++j) { dh[j] = hi[j]; dl[j] = lo[j]; }
}

// hp0[bg][c 16][k 512] u32 = hi | lo<<16 of h0[b][k]; zero 256 flags
__global__ __launch_bounds__(256) void k_prep_h(const float* __restrict__ h0,
                                                unsigned* __restrict__ hp0,
                                                unsigned* __restrict__ flags)
{
  int idx = blockIdx.x * 256 + threadIdx.x;   // 0..65535
  int k = idx & 511, c = (idx >> 9) & 15, bg = idx >> 13;
  float v = h0[(size_t)(bg * 16 + c) * HID + k];
  unsigned short hi = bf_hi(v);
  unsigned short lo = bf_hi(v - bf_val(hi));
  hp0[idx] = (unsigned)hi | ((unsigned)lo << 16);
  if (blockIdx.x == 0 && threadIdx.x < 256) flags[threadIdx.x] = 0;
}

// ---------------- persistent MFMA LSTM, 2 interleaved recurrences ----------------
// 128 blocks = 32 ug (16 units) x 4 pairs. Block handles bgA=2p and bgB=2p+1,
// alternating phases; each phase's sync latency hides under the other's compute.
// Sync/transport mechanics identical to round 6 (agent-scope relaxed atomics).
__global__ __launch_bounds__(NTHR, 2) void k_persist(
    const unsigned short* __restrict__ xp,   // [t*8+bg][2][16][128]
    const unsigned short* __restrict__ wf,   // A-fragments
    const float* __restrict__ bih, const float* __restrict__ bhh,
    unsigned* __restrict__ hp0,              // [8][16][512] packed hi|lo<<16
    unsigned* __restrict__ hp1,
    const float* __restrict__ c0,            // [128][512]
    const int* __restrict__ len,
    float* __restrict__ out,                 // [128][512]
    unsigned* __restrict__ flags)            // [8][32]
{
  extern __shared__ char smem[];
  short* zplA  = (short*)smem;                         // [2][16][PK]
  short* zplB  = zplA + Z_SHORTS;                      // [2][16][PK]
  float* gates = (float*)(smem + 2 * Z_SHORTS * 2);    // [4 kq][4 q][16 u][GSTR]

  const int blk = blockIdx.x;
  const int ug = blk & 31, pr = blk >> 5;
  const int bgA = pr * 2, bgB = pr * 2 + 1;
  const int tid = threadIdx.x;
  const int w = tid >> 6, l = tid & 63;
  const int kq = w & 3, th = w >> 2;
  const int cB = l & 15, gch = l >> 4;
  const int q0 = th * 2, q1 = th * 2 + 1;

  // ---- load 20 W A-fragments into NAMED registers (once; live in AGPRs)
  const uint4* wfq = (const uint4*)wf;
#define LDW(q_, s_, p_) \
  (*reinterpret_cast<const bf16x8*>(&wfq[(size_t)((((ug * 4 + (q_)) * 4 + kq) * 5 + (s_)) * 2 + (p_)) * 64 + l]))
  bf16x8 Aa0h = LDW(q0,0,0), Aa0l = LDW(q0,0,1), Aa1h = LDW(q0,1,0), Aa1l = LDW(q0,1,1);
  bf16x8 Aa2h = LDW(q0,2,0), Aa2l = LDW(q0,2,1), Aa3h = LDW(q0,3,0), Aa3l = LDW(q0,3,1);
  bf16x8 Aa4h = LDW(q0,4,0), Aa4l = LDW(q0,4,1);
  bf16x8 Ab0h = LDW(q1,0,0), Ab0l = LDW(q1,0,1), Ab1h = LDW(q1,1,0), Ab1l = LDW(q1,1,1);
  bf16x8 Ab2h = LDW(q1,2,0), Ab2l = LDW(q1,2,1), Ab3h = LDW(q1,3,0), Ab3l = LDW(q1,3,1);
  bf16x8 Ab4h = LDW(q1,4,0), Ab4l = LDW(q1,4,1);
#undef LDW
  asm volatile("" : "+v"(Aa0h), "+v"(Aa0l), "+v"(Aa1h), "+v"(Aa1l), "+v"(Aa2h),
                    "+v"(Aa2l), "+v"(Aa3h), "+v"(Aa3l), "+v"(Aa4h), "+v"(Aa4l),
                    "+v"(Ab0h), "+v"(Ab0l), "+v"(Ab1h), "+v"(Ab1l), "+v"(Ab2h),
                    "+v"(Ab2l), "+v"(Ab3h), "+v"(Ab3l), "+v"(Ab4h), "+v"(Ab4l));

  // ---- per-cell state for BOTH recurrences (threads 0..255: cell (cb, cu))
  const int cb = tid & 15, cu = (tid >> 4) & 15;
  const int gbA = bgA * 16 + cb, gbB = bgB * 16 + cb;
  const int hu = ug * 16 + cu;
  float cA = 0.f, cBv = 0.f, bsq[4] = {0.f, 0.f, 0.f, 0.f};
  int lenA = -1, lenB = -1;
  if (tid < 256) {
    cA  = c0[(size_t)gbA * HID + hu];
    cBv = c0[(size_t)gbB * HID + hu];
    lenA = len[gbA];
    lenB = len[gbB];
    #pragma unroll
    for (int q = 0; q < 4; ++q) bsq[q] = bih[q * HID + hu] + bhh[q * HID + hu];
  }

  unsigned* flagsA = flags + bgA * 32;
  unsigned* flagsB = flags + bgB * 32;

  // ---- prologue: stage xA(0) into zplA x-region
  {
    const uint4* xps = (const uint4*)(xp + (size_t)(0 * 8 + bgA) * 4096);
    uint4 xa = xps[tid];
    int p = tid >> 8, c = (tid >> 4) & 15, kc = tid & 15;
    *(uint4*)(zplA + (p * 16 + c) * PK + kc * 8) = xa;
  }

#define KSTEP(ZP, s_, AH0, AL0, AH1, AL1)                                      \
  {                                                                            \
    int ka = kq * 160 + (s_) * 32 + gch * 8;                                   \
    bf16x8 Bh = *(const bf16x8*)((ZP) + cB * PK + ka);                         \
    bf16x8 Bl = *(const bf16x8*)((ZP) + (16 + cB) * PK + ka);                  \
    acc0 = __builtin_amdgcn_mfma_f32_16x16x32_bf16(AH0, Bh, acc0, 0, 0, 0);    \
    acc0 = __builtin_amdgcn_mfma_f32_16x16x32_bf16(AH0, Bl, acc0, 0, 0, 0);    \
    acc0 = __builtin_amdgcn_mfma_f32_16x16x32_bf16(AL0, Bh, acc0, 0, 0, 0);    \
    acc1 = __builtin_amdgcn_mfma_f32_16x16x32_bf16(AH1, Bh, acc1, 0, 0, 0);    \
    acc1 = __builtin_amdgcn_mfma_f32_16x16x32_bf16(AH1, Bl, acc1, 0, 0, 0);    \
    acc1 = __builtin_amdgcn_mfma_f32_16x16x32_bf16(AL1, Bh, acc1, 0, 0, 0);    \
  }

  // One LSTM phase for one bg. ZSELF holds (x staged earlier + h staged here);
  // pre-stages the x-tile XOIDX into ZOTHER for the other recurrence's phase.
#define PHASE(FLG, HSRC, HDST, ZSELF, ZOTHER, XOIDX, CREG, MYLEN, GB)          \
  {                                                                            \
    if (t) {                                                                   \
      if (tid < 32) {                                                          \
        const unsigned* fp = (FLG) + tid;                                      \
        while (__hip_atomic_load(fp, __ATOMIC_RELAXED,                         \
                                 __HIP_MEMORY_SCOPE_AGENT) < (unsigned)t)      \
          __builtin_amdgcn_s_sleep(1);                                         \
      }                                                                        \
    }                                                                          \
    __syncthreads();                                                           \
    unsigned long long hch[8];                                                 \
    const unsigned long long* hq = (const unsigned long long*)(HSRC);          \
    _Pragma("unroll")                                                          \
    for (int j = 0; j < 8; ++j)                                                \
      hch[j] = __hip_atomic_load(hq + j * 512 + tid, __ATOMIC_RELAXED,         \
                                 __HIP_MEMORY_SCOPE_AGENT);                    \
    uint4 xo = ((const uint4*)(xp + (size_t)(XOIDX) * 4096))[tid];             \
    _Pragma("unroll")                                                          \
    for (int j = 0; j < 8; ++j) {                                              \
      int ci = j * 512 + tid;                                                  \
      int c = ci >> 8, kp = ci & 255;                                          \
      unsigned w0 = (unsigned)hch[j], w1 = (unsigned)(hch[j] >> 32);           \
      unsigned hipair = (w0 & 0xFFFFu) | (w1 << 16);                           \
      unsigned lopair = (w0 >> 16) | (w1 & 0xFFFF0000u);                       \
      *(unsigned*)((ZSELF) + c * PK + 128 + 2 * kp)        = hipair;           \
      *(unsigned*)((ZSELF) + (16 + c) * PK + 128 + 2 * kp) = lopair;           \
    }                                                                          \
    {                                                                          \
      int p = tid >> 8, c = (tid >> 4) & 15, kc = tid & 15;                    \
      *(uint4*)((ZOTHER) + (p * 16 + c) * PK + kc * 8) = xo;                   \
    }                                                                          \
    __syncthreads();                                                           \
    f32x4 acc0 = {0, 0, 0, 0}, acc1 = {0, 0, 0, 0};                            \
    KSTEP(ZSELF, 0, Aa0h, Aa0l, Ab0h, Ab0l)                                    \
    KSTEP(ZSELF, 1, Aa1h, Aa1l, Ab1h, Ab1l)                                    \
    KSTEP(ZSELF, 2, Aa2h, Aa2l, Ab2h, Ab2l)                                    \
    KSTEP(ZSELF, 3, Aa3h, Aa3l, Ab3h, Ab3l)                                    \
    KSTEP(ZSELF, 4, Aa4h, Aa4l, Ab4h, Ab4l)                                    \
    _Pragma("unroll")                                                          \
    for (int rr = 0; rr < 4; ++rr) {                                           \
      gates[((kq * 4 + q0) * 16 + gch * 4 + rr) * GSTR + cB] = acc0[rr];       \
      gates[((kq * 4 + q1) * 16 + gch * 4 + rr) * GSTR + cB] = acc1[rr];       \
    }                                                                          \
    __syncthreads();                                                           \
    if (tid < 256) {                                                           \
      float s4[4];                                                             \
      _Pragma("unroll")                                                        \
      for (int q = 0; q < 4; ++q) {                                            \
        float s = bsq[q];                                                      \
        _Pragma("unroll")                                                      \
        for (int kp = 0; kp < 4; ++kp)                                         \
          s += gates[((kp * 4 + q) * 16 + cu) * GSTR + cb];                    \
        s4[q] = s;                                                             \
      }                                                                        \
      float iv = fsigmoid(s4[0]);                                              \
      float fv = fsigmoid(s4[1]);                                              \
      float gv = ftanh(s4[2]);                                                 \
      float ov = fsigmoid(s4[3]);                                              \
      (CREG) = fv * (CREG) + iv * gv;                                          \
      float h2 = ov * ftanh(CREG);                                             \
      unsigned short hh = bf_hi(h2);                                           \
      unsigned short ll = bf_hi(h2 - bf_val(hh));                              \
      __hip_atomic_store((HDST) + (size_t)cb * 512 + hu,                       \
                         (unsigned)hh | ((unsigned)ll << 16),                  \
                         __ATOMIC_RELAXED, __HIP_MEMORY_SCOPE_AGENT);          \
      if (t == (MYLEN) - 1) out[(size_t)(GB) * HID + hu] = h2;                 \
    }                                                                          \
    __syncthreads(); /* vmcnt(0) drain: h stores visible before flag */        \
    if (tid == 0)                                                              \
      __hip_atomic_store((FLG) + ug, (unsigned)(t + 1),                        \
                         __ATOMIC_RELAXED, __HIP_MEMORY_SCOPE_AGENT);          \
  }

  for (int t = 0; t < T_STEPS; ++t) {
    const unsigned* hsA = ((t & 1) ? hp1 : hp0) + (size_t)bgA * 8192;
    unsigned*       hdA = ((t & 1) ? hp0 : hp1) + (size_t)bgA * 8192;
    const unsigned* hsB = ((t & 1) ? hp1 : hp0) + (size_t)bgB * 8192;
    unsigned*       hdB = ((t & 1) ? hp0 : hp1) + (size_t)bgB * 8192;
    const int tn = (t + 1 < T_STEPS) ? t + 1 : t;

    // phase A: compute bgA step t; pre-stage xB(t) into zplB
    PHASE(flagsA, hsA, hdA, zplA, zplB, t * 8 + bgB, cA, lenA, gbA)
    // phase B: compute bgB step t; pre-stage xA(t+1) into zplA
    PHASE(flagsB, hsB, hdB, zplB, zplA, tn * 8 + bgA, cBv, lenB, gbB)
  }
#undef PHASE
#undef KSTEP
}

// ---------------- launch ----------------
extern "C" void kernel_launch(void* const* d_in, const int* in_sizes, int n_in,
                              void* d_out, int out_size, void* d_ws, size_t ws_size,
                              hipStream_t stream)
{
  const float* inputs = (const float*)d_in[0];
  const int*   len    = (const int*)  d_in[1];
  const float* h0     = (const float*)d_in[2];
  const float* c0     = (const float*)d_in[3];
  const float* Wih    = (const float*)d_in[4];
  const float* Whh    = (const float*)d_in[5];
  const float* bih    = (const float*)d_in[6];
  const float* bhh    = (const float*)d_in[7];
  float* out = (float*)d_out;

  char* p = (char*)d_ws;
  unsigned short* xp = (unsigned short*)p; p += (size_t)T_STEPS * 8 * 4096 * 2;      // 64 MB
  unsigned short* wf = (unsigned short*)p; p += (size_t)2560 * 2 * 64 * 8 * 2;       // 5 MB
  unsigned* hp0 = (unsigned*)p;  p += (size_t)8 * 16 * 512 * 4;                      // 256 KB
  unsigned* hp1 = (unsigned*)p;  p += (size_t)8 * 16 * 512 * 4;                      // 256 KB
  unsigned* flags = (unsigned*)p; p += 256 * 4;

  (void)hipFuncSetAttribute((const void*)k_persist,
                            hipFuncAttributeMaxDynamicSharedMemorySize, SMEM_BYTES);

  k_prep_x<<<T_STEPS * 8, 256, 0, stream>>>(inputs, xp);
  k_prep_w<<<2560, 64, 0, stream>>>(Wih, Whh, wf);
  k_prep_h<<<256, 256, 0, stream>>>(h0, hp0, flags);

  void* args[] = {(void*)&xp, (void*)&wf, (void*)&bih, (void*)&bhh,
                  (void*)&hp0, (void*)&hp1, (void*)&c0, (void*)&len,
                  (void*)&out, (void*)&flags};
  (void)hipLaunchCooperativeKernel((void*)k_persist, dim3(NBLK), dim3(NTHR),
                                   args, SMEM_BYTES, stream);
}

// Round 10
// 3774.432 us; speedup vs baseline: 1.3117x; 1.3117x over previous
//
#include <hip/hip_runtime.h>
#include <hip/hip_bf16.h>
#include <cstdint>
#include <cstddef>

#define T_STEPS 1024
#define BATCH   128
#define INF     128   // used input features (130 minus last 2)
#define HID     512
#define NBLK    256   // 32 ug (16 units) x 8 bg (16 batch)
#define NTHR    512   // 8 waves: u4 = w&3 (4-unit tile), kh = w>>2 (320-deep k half)
#define PK      648   // padded k stride (bf16 units) in LDS Z planes
#define Z_SHORTS    (2 * 16 * PK)            // one Z buffer: 2 planes x 16 c x PK
#define Z_BYTES     (Z_SHORTS * 2)           // 41472 B
#define RED_BYTES   (256 * 16)               // 4 tiles x 64 lanes x f32x4
#define SMEM_BYTES  (2 * Z_BYTES + RED_BYTES)   // 87040 B

typedef short  bf16x8 __attribute__((ext_vector_type(8)));
typedef float  f32x4  __attribute__((ext_vector_type(4)));

static __device__ __forceinline__ unsigned short bf_hi(float v) {
  __hip_bfloat16 h = __float2bfloat16(v);
  return *reinterpret_cast<unsigned short*>(&h);
}
static __device__ __forceinline__ float bf_val(unsigned short u) {
  __hip_bfloat16 h = *reinterpret_cast<__hip_bfloat16*>(&u);
  return __bfloat162float(h);
}
static __device__ __forceinline__ float fsigmoid(float x) {
  return 1.f / (1.f + __expf(-x));
}
static __device__ __forceinline__ float ftanh(float x) {
  return 1.f - 2.f / (__expf(2.f * x) + 1.f);
}

// ---------------- pre-pass kernels ----------------

// xp[t*8+bg][p][c 16][k 128] bf16 (p=0 hi, p=1 lo)
__global__ __launch_bounds__(256) void k_prep_x(const float* __restrict__ in,
                                                unsigned short* __restrict__ xp)
{
  int t = blockIdx.x >> 3, bg = blockIdx.x & 7;
  int tid = threadIdx.x;
  size_t base = (size_t)blockIdx.x * 4096;
  #pragma unroll
  for (int rep = 0; rep < 8; ++rep) {
    int idx = rep * 256 + tid;           // 0..2047
    int c = idx >> 7, k = idx & 127;
    float v = in[((size_t)(bg * 16 + c) * T_STEPS + t) * 130 + k];
    unsigned short hi = bf_hi(v);
    unsigned short lo = bf_hi(v - bf_val(hi));
    xp[base + c * 128 + k]        = hi;
    xp[base + 2048 + c * 128 + k] = lo;
  }
}

// W A-fragments, bf16 hi/lo, per-lane MFMA layout.
// blk = ((ug*4+u4)*2+kh)*10+s  (2560 blocks x 64 threads)
// tile rows m = u_loc*4 + gate  (u_loc = m>>2, g = m&3)  -> lane-local cell!
// A lane map (16x16x32): row = l&15, k = (l>>4)*8 + j
__global__ __launch_bounds__(64) void k_prep_w(const float* __restrict__ Wih,
                                               const float* __restrict__ Whh,
                                               unsigned short* __restrict__ wf)
{
  int blk = blockIdx.x;
  int s = blk % 10; int r = blk / 10;
  int kh = r & 1; int u4 = (r >> 1) & 3; int ug = r >> 3;
  int l = threadIdx.x;
  int m = l & 15;
  int Grow = (m & 3) * HID + ug * 16 + u4 * 4 + (m >> 2);
  int kb = kh * 320 + s * 32 + (l >> 4) * 8;
  float v[8];
  #pragma unroll
  for (int j = 0; j < 8; ++j)
    v[j] = (kb < INF) ? Wih[(size_t)Grow * INF + kb + j]
                      : Whh[(size_t)Grow * HID + (kb - INF) + j];
  unsigned short hi[8], lo[8];
  #pragma unroll
  for (int j = 0; j < 8; ++j) {
    hi[j] = bf_hi(v[j]);
    lo[j] = bf_hi(v[j] - bf_val(hi[j]));
  }
  unsigned short* dh = wf + ((size_t)(blk * 2 + 0) * 64 + l) * 8;
  unsigned short* dl = wf + ((size_t)(blk * 2 + 1) * 64 + l) * 8;
  #pragma unroll
  for (int j = 0; j < 8; ++j) { dh[j] = hi[j]; dl[j] = lo[j]; }
}

// hp0[bg][u 512][c 16] u64 = tag0<<32 | (hi | lo<<16) of h0[b][u]
__global__ __launch_bounds__(256) void k_prep_h(const float* __restrict__ h0,
                                                unsigned long long* __restrict__ hp0)
{
  int idx = blockIdx.x * 256 + threadIdx.x;   // 0..65535
  int bg = idx >> 13;
  int r = idx & 8191;
  int u = r >> 4, c = r & 15;
  float v = h0[(size_t)(bg * 16 + c) * HID + u];
  unsigned short hi = bf_hi(v);
  unsigned short lo = bf_hi(v - bf_val(hi));
  hp0[idx] = (unsigned long long)((unsigned)hi | ((unsigned)lo << 16));  // tag 0
}

// ---------------- persistent MFMA LSTM (tagged-h, flagless) ----------------
// 256 blocks = 32 ug (16 units) x 8 bg (16 b). 1 block/CU.
// 8 waves: u4 = w&3 (tile of 4 units x 4 gates), kh = w>>2 (320-deep k half).
// Lane acc[0..3] = i,f,g,o of cell (unit l>>4 of tile, batch l&15) -> in-lane
// cell update. Sync: consumers poll step-tagged h u64 words; no flags.
__global__ __launch_bounds__(NTHR, 2) void k_persist(
    const unsigned short* __restrict__ xp,   // [t*8+bg][2][16][128]
    const unsigned short* __restrict__ wf,   // A-fragments
    const float* __restrict__ bih, const float* __restrict__ bhh,
    unsigned long long* __restrict__ hp0,    // [8][512][16] tagged u64
    unsigned long long* __restrict__ hp1,
    const float* __restrict__ c0,            // [128][512]
    const int* __restrict__ len,
    float* __restrict__ out)                 // [128][512]
{
  extern __shared__ char smem[];
  short* zpl = (short*)smem;                       // [2 dbuf][2 plane][16 c][PK]
  f32x4* red = (f32x4*)(smem + 2 * Z_BYTES);       // [4 tiles][64 lanes]

  const int blk = blockIdx.x;
  const int ug = blk & 31, bg = blk >> 5;
  const int tid = threadIdx.x;
  const int w = tid >> 6, l = tid & 63;
  const int u4 = w & 3, kh = w >> 2;
  const int cB = l & 15, gch = l >> 4;

  // ---- load 20 W A-fragments into NAMED registers (once; live in AGPRs)
  const uint4* wfq = (const uint4*)wf;
  const int fbase = ((ug * 4 + u4) * 2 + kh) * 10;
#define LDW(s_, p_) \
  (*reinterpret_cast<const bf16x8*>(&wfq[(size_t)((fbase + (s_)) * 2 + (p_)) * 64 + l]))
  bf16x8 A0h = LDW(0,0), A0l = LDW(0,1), A1h = LDW(1,0), A1l = LDW(1,1);
  bf16x8 A2h = LDW(2,0), A2l = LDW(2,1), A3h = LDW(3,0), A3l = LDW(3,1);
  bf16x8 A4h = LDW(4,0), A4l = LDW(4,1), A5h = LDW(5,0), A5l = LDW(5,1);
  bf16x8 A6h = LDW(6,0), A6l = LDW(6,1), A7h = LDW(7,0), A7l = LDW(7,1);
  bf16x8 A8h = LDW(8,0), A8l = LDW(8,1), A9h = LDW(9,0), A9l = LDW(9,1);
#undef LDW
  asm volatile("" : "+v"(A0h), "+v"(A0l), "+v"(A1h), "+v"(A1l), "+v"(A2h),
                    "+v"(A2l), "+v"(A3h), "+v"(A3l), "+v"(A4h), "+v"(A4l),
                    "+v"(A5h), "+v"(A5l), "+v"(A6h), "+v"(A6l), "+v"(A7h),
                    "+v"(A7l), "+v"(A8h), "+v"(A8l), "+v"(A9h), "+v"(A9l));

  // ---- per-cell state: waves 0..3 lanes own cell (unit hu, batch cb)
  const int cb = l & 15;
  const int hu = ug * 16 + u4 * 4 + (l >> 4);   // valid for w<4
  const int gb = bg * 16 + cb;
  float c_reg = 0.f, bsq[4] = {0.f, 0.f, 0.f, 0.f};
  int mylen = -1;
  if (tid < 256) {
    c_reg = c0[(size_t)gb * HID + hu];
    mylen = len[gb];
    #pragma unroll
    for (int g = 0; g < 4; ++g) bsq[g] = bih[g * HID + hu] + bhh[g * HID + hu];
  }

  // consumer poll assignment: c = tid&15, qq = tid>>4; pairs of adjacent units
  const int pc = tid & 15, qq = tid >> 4;
  const int pbase = 32 * qq + pc;   // u64 word index base

  for (int t = 0; t < T_STEPS; ++t) {
    short* zcur = zpl + (t & 1) * Z_SHORTS;
    const unsigned long long* hq = ((t & 1) ? hp1 : hp0) + (size_t)bg * 8192;
    unsigned long long*       hd = ((t & 1) ? hp0 : hp1) + (size_t)bg * 8192;

    // ---- issue x load (independent of h; overlaps the poll)
    uint4 xv = ((const uint4*)(xp + (size_t)(t * 8 + bg) * 4096))[tid];

    // ---- poll tagged h: 16 words (8 adjacent-unit pairs), retry stale
    unsigned long long hch[16];
    #pragma unroll
    for (int j = 0; j < 16; ++j)
      hch[j] = __hip_atomic_load(hq + 1024 * (j >> 1) + 16 * (j & 1) + pbase,
                                 __ATOMIC_RELAXED, __HIP_MEMORY_SCOPE_AGENT);
    for (;;) {
      int bad = 0;
      #pragma unroll
      for (int j = 0; j < 16; ++j)
        if ((unsigned)(hch[j] >> 32) != (unsigned)t) {
          hch[j] = __hip_atomic_load(hq + 1024 * (j >> 1) + 16 * (j & 1) + pbase,
                                     __ATOMIC_RELAXED, __HIP_MEMORY_SCOPE_AGENT);
          bad = 1;
        }
      if (!__any(bad)) break;
      __builtin_amdgcn_s_sleep(1);
    }

    // ---- stage: x straight copy + h unpack (paired u32 writes), then barrier
    {
      int p_ = tid >> 8, c_ = (tid >> 4) & 15, kc = tid & 15;
      *(uint4*)(zcur + (p_ * 16 + c_) * PK + kc * 8) = xv;
    }
    #pragma unroll
    for (int p = 0; p < 8; ++p) {
      unsigned e0 = (unsigned)hch[2 * p], e1 = (unsigned)hch[2 * p + 1];
      unsigned hipair = (e0 & 0xFFFFu) | (e1 << 16);
      unsigned lopair = (e0 >> 16) | (e1 & 0xFFFF0000u);
      int off = pc * PK + 128 + 64 * p + 2 * qq;
      *(unsigned*)(zcur + off)           = hipair;
      *(unsigned*)(zcur + 16 * PK + off) = lopair;
    }
    __syncthreads();   // (1) staging complete -> MFMA may read

    // ---- MFMA: one 4-unit x 4-gate tile over this wave's 320-k half
    f32x4 accE = {0, 0, 0, 0}, accO = {0, 0, 0, 0};
#define KSTEP(s_, AH, AL, ACC)                                                 \
  {                                                                            \
    int ka = kh * 320 + (s_) * 32 + gch * 8;                                   \
    bf16x8 Bh = *(const bf16x8*)(zcur + cB * PK + ka);                         \
    bf16x8 Bl = *(const bf16x8*)(zcur + 16 * PK + cB * PK + ka);               \
    ACC = __builtin_amdgcn_mfma_f32_16x16x32_bf16(AH, Bh, ACC, 0, 0, 0);       \
    ACC = __builtin_amdgcn_mfma_f32_16x16x32_bf16(AH, Bl, ACC, 0, 0, 0);       \
    ACC = __builtin_amdgcn_mfma_f32_16x16x32_bf16(AL, Bh, ACC, 0, 0, 0);       \
  }
    KSTEP(0, A0h, A0l, accE) KSTEP(1, A1h, A1l, accO)
    KSTEP(2, A2h, A2l, accE) KSTEP(3, A3h, A3l, accO)
    KSTEP(4, A4h, A4l, accE) KSTEP(5, A5h, A5l, accO)
    KSTEP(6, A6h, A6l, accE) KSTEP(7, A7h, A7l, accO)
    KSTEP(8, A8h, A8l, accE) KSTEP(9, A9h, A9l, accO)
#undef KSTEP
    f32x4 acc = accE + accO;

    // ---- pair-merge the two k-halves (waves 4-7 -> LDS, waves 0-3 add)
    if (w >= 4) red[u4 * 64 + l] = acc;
    __syncthreads();   // (2)
    if (tid < 256) {
      f32x4 o = red[u4 * 64 + l];
      float s0 = acc[0] + o[0] + bsq[0];
      float s1 = acc[1] + o[1] + bsq[1];
      float s2 = acc[2] + o[2] + bsq[2];
      float s3 = acc[3] + o[3] + bsq[3];
      float iv = fsigmoid(s0);
      float fv = fsigmoid(s1);
      float gv = ftanh(s2);
      float ov = fsigmoid(s3);
      c_reg = fv * c_reg + iv * gv;
      float h2 = ov * ftanh(c_reg);
      unsigned short hh = bf_hi(h2);
      unsigned short ll = bf_hi(h2 - bf_val(hh));
      unsigned long long word = ((unsigned long long)(unsigned)(t + 1) << 32)
                              | (unsigned long long)((unsigned)hh | ((unsigned)ll << 16));
      __hip_atomic_store(hd + hu * 16 + cb, word,
                         __ATOMIC_RELAXED, __HIP_MEMORY_SCOPE_AGENT);
      if (t == mylen - 1) out[(size_t)gb * HID + hu] = h2;
    }
    // no trailing barrier: next iteration's poll gates peers; Z dbuf + red
    // ordering proven via own-block store->poll transitivity.
  }
}

// ---------------- launch ----------------
extern "C" void kernel_launch(void* const* d_in, const int* in_sizes, int n_in,
                              void* d_out, int out_size, void* d_ws, size_t ws_size,
                              hipStream_t stream)
{
  const float* inputs = (const float*)d_in[0];
  const int*   len    = (const int*)  d_in[1];
  const float* h0     = (const float*)d_in[2];
  const float* c0     = (const float*)d_in[3];
  const float* Wih    = (const float*)d_in[4];
  const float* Whh    = (const float*)d_in[5];
  const float* bih    = (const float*)d_in[6];
  const float* bhh    = (const float*)d_in[7];
  float* out = (float*)d_out;

  char* p = (char*)d_ws;
  unsigned short* xp = (unsigned short*)p; p += (size_t)T_STEPS * 8 * 4096 * 2;      // 64 MB
  unsigned short* wf = (unsigned short*)p; p += (size_t)2560 * 2 * 64 * 8 * 2;       // 5 MB
  unsigned long long* hp0 = (unsigned long long*)p; p += (size_t)8 * 8192 * 8;       // 512 KB
  unsigned long long* hp1 = (unsigned long long*)p; p += (size_t)8 * 8192 * 8;       // 512 KB

  (void)hipFuncSetAttribute((const void*)k_persist,
                            hipFuncAttributeMaxDynamicSharedMemorySize, SMEM_BYTES);

  k_prep_x<<<T_STEPS * 8, 256, 0, stream>>>(inputs, xp);
  k_prep_w<<<2560, 64, 0, stream>>>(Wih, Whh, wf);
  k_prep_h<<<256, 256, 0, stream>>>(h0, hp0);

  void* args[] = {(void*)&xp, (void*)&wf, (void*)&bih, (void*)&bhh,
                  (void*)&hp0, (void*)&hp1, (void*)&c0, (void*)&len,
                  (void*)&out};
  (void)hipLaunchCooperativeKernel((void*)k_persist, dim3(NBLK), dim3(NTHR),
                                   args, SMEM_BYTES, stream);
}

// Round 11
// 3269.502 us; speedup vs baseline: 1.5143x; 1.1544x over previous
//
#include <hip/hip_runtime.h>
#include <hip/hip_bf16.h>
#include <cstdint>
#include <cstddef>

#define T_STEPS 1024
#define BATCH   128
#define INF     128   // used input features (130 minus last 2)
#define HID     512
#define NBLK    256   // 32 ug (16 units) x 8 bg (16 batch), 1 block/CU
#define NTHR    256   // 4 waves; wave w = u-tile (4 units x 4 gates), full k=640
#define PK      648   // padded k stride (fp16 units) in LDS Z plane (row 1296B, 16B-mult)

typedef _Float16 f16x8 __attribute__((ext_vector_type(8)));
typedef float    f32x4 __attribute__((ext_vector_type(4)));

static __device__ __forceinline__ unsigned short f16b(float v) {
  _Float16 h = (_Float16)v;
  unsigned short u;
  __builtin_memcpy(&u, &h, 2);
  return u;
}
static __device__ __forceinline__ float fsigmoid(float x) {
  return 1.f / (1.f + __expf(-x));
}
static __device__ __forceinline__ float ftanh(float x) {
  return 1.f - 2.f / (__expf(2.f * x) + 1.f);
}

// ---------------- pre-pass kernels ----------------

// xp[t*8+bg][c 16][k 128] fp16
__global__ __launch_bounds__(256) void k_prep_x(const float* __restrict__ in,
                                                unsigned short* __restrict__ xp)
{
  int t = blockIdx.x >> 3, bg = blockIdx.x & 7;
  int tid = threadIdx.x;
  size_t base = (size_t)blockIdx.x * 2048;
  #pragma unroll
  for (int rep = 0; rep < 8; ++rep) {
    int idx = rep * 256 + tid;           // 0..2047
    int c = idx >> 7, k = idx & 127;
    float v = in[((size_t)(bg * 16 + c) * T_STEPS + t) * 130 + k];
    xp[base + c * 128 + k] = f16b(v);
  }
}

// W A-fragments fp16, per-lane MFMA layout.
// blk = (ug*4+u4)*20 + s   (2560 blocks x 64 threads)
// tile rows m = u_loc*4 + gate -> Grow = gate*HID + ug*16 + u4*4 + u_loc
// A lane map (16x16x32): row = l&15, k = (l>>4)*8 + j
__global__ __launch_bounds__(64) void k_prep_w(const float* __restrict__ Wih,
                                               const float* __restrict__ Whh,
                                               unsigned short* __restrict__ wf)
{
  int blk = blockIdx.x;
  int s = blk % 20; int r = blk / 20;
  int u4 = r & 3; int ug = r >> 2;
  int l = threadIdx.x;
  int m = l & 15;
  int Grow = (m & 3) * HID + ug * 16 + u4 * 4 + (m >> 2);
  int kb = s * 32 + (l >> 4) * 8;
  unsigned short o[8];
  #pragma unroll
  for (int j = 0; j < 8; ++j) {
    float v = (kb + j < INF) ? Wih[(size_t)Grow * INF + kb + j]
                             : Whh[(size_t)Grow * HID + (kb + j - INF)];
    o[j] = f16b(v);
  }
  unsigned short* d = wf + ((size_t)blk * 64 + l) * 8;
  #pragma unroll
  for (int j = 0; j < 8; ++j) d[j] = o[j];
}

// hp0[bg][c 16][u 512] fp16 of h0; zero 256 flags
__global__ __launch_bounds__(256) void k_prep_h(const float* __restrict__ h0,
                                                unsigned short* __restrict__ hp0,
                                                unsigned* __restrict__ flags)
{
  int idx = blockIdx.x * 256 + threadIdx.x;   // 0..65535
  int bg = idx >> 13;
  int r = idx & 8191;
  int c = r >> 9, u = r & 511;
  hp0[idx] = f16b(h0[(size_t)(bg * 16 + c) * HID + u]);
  if (blockIdx.x == 0 && threadIdx.x < 256) flags[threadIdx.x] = 0;
}

// ---------------- persistent MFMA LSTM (fp16 single-plane) ----------------
// 256 blocks = 32 ug (16 units) x 8 bg (16 b). 256 thr = 4 waves.
// Wave w owns u-tile (units ug*16+w*4 .. +3, rows = u_loc*4+gate), full k=640:
// 20 x mfma_f32_16x16x32_f16 with 20 named A-frags (AGPR-resident).
// Lane acc[0..3] = i,f,g,o of cell (unit = w*4 + (l>>4), batch = l&15) ->
// in-lane cell update, shfl-pack fp16 pair, one u32 agent store.
// Sync = r6 proven scheme: per-wave 32-flag poll, bulk h load, 2 barriers/step.
__global__ __launch_bounds__(NTHR, 1) void k_persist(
    const unsigned short* __restrict__ xp,   // [t*8+bg][16][128] fp16
    const unsigned short* __restrict__ wf,   // A-fragments fp16
    const float* __restrict__ bih, const float* __restrict__ bhh,
    unsigned short* __restrict__ hp0,        // [8][16][512] fp16 ping
    unsigned short* __restrict__ hp1,        // pong
    const float* __restrict__ c0,            // [128][512]
    const int* __restrict__ len,
    float* __restrict__ out,                 // [128][512]
    unsigned* __restrict__ flags)            // [8][32]
{
  __shared__ short zpl[16][PK];              // [c 16][k 640 pad 648] fp16

  const int blk = blockIdx.x;
  const int ug = blk & 31, bg = blk >> 5;
  const int tid = threadIdx.x;
  const int w = tid >> 6, l = tid & 63;
  const int cB = l & 15, gch = l >> 4;

  // ---- load 20 W A-fragments into NAMED registers (once; AGPR-resident)
  const uint4* wfq = (const uint4*)wf;
  const int fb = (ug * 4 + w) * 20;
#define LDW(s_) (*reinterpret_cast<const f16x8*>(&wfq[(size_t)(fb + (s_)) * 64 + l]))
  f16x8 A0 = LDW(0),  A1 = LDW(1),  A2 = LDW(2),  A3 = LDW(3),  A4 = LDW(4);
  f16x8 A5 = LDW(5),  A6 = LDW(6),  A7 = LDW(7),  A8 = LDW(8),  A9 = LDW(9);
  f16x8 A10 = LDW(10), A11 = LDW(11), A12 = LDW(12), A13 = LDW(13), A14 = LDW(14);
  f16x8 A15 = LDW(15), A16 = LDW(16), A17 = LDW(17), A18 = LDW(18), A19 = LDW(19);
#undef LDW
  asm volatile("" : "+v"(A0), "+v"(A1), "+v"(A2), "+v"(A3), "+v"(A4),
                    "+v"(A5), "+v"(A6), "+v"(A7), "+v"(A8), "+v"(A9),
                    "+v"(A10), "+v"(A11), "+v"(A12), "+v"(A13), "+v"(A14),
                    "+v"(A15), "+v"(A16), "+v"(A17), "+v"(A18), "+v"(A19));

  // ---- per-cell state: every lane owns cell (unit hu, batch cb)
  const int cb = l & 15;
  const int hu = ug * 16 + w * 4 + (l >> 4);
  const int gb = bg * 16 + cb;
  float c_reg = c0[(size_t)gb * HID + hu];
  const int mylen = len[gb];
  float bsq[4];
  #pragma unroll
  for (int g = 0; g < 4; ++g) bsq[g] = bih[g * HID + hu] + bhh[g * HID + hu];

  const unsigned* fl = flags + bg * 32;
  const int hc = tid >> 4, hj = tid & 15;   // h stage assignment

  for (int t = 0; t < T_STEPS; ++t) {
    // ---- x load first (h-independent; latency hides under the poll)
    uint4 xv = ((const uint4*)(xp + (size_t)(t * 8 + bg) * 2048))[tid];

    // ---- per-wave poll of the 32 peer flags (cheap detect, r6 scheme)
    if (t) {
      const unsigned* fp = fl + (l & 31);
      for (;;) {
        unsigned v = __hip_atomic_load(fp, __ATOMIC_RELAXED,
                                       __HIP_MEMORY_SCOPE_AGENT);
        if (__all((int)(v >= (unsigned)t))) break;
        __builtin_amdgcn_s_sleep(1);
      }
    }
    const unsigned long long* hq =
        (const unsigned long long*)(((t & 1) ? hp1 : hp0) + (size_t)bg * 8192);
    unsigned* hdw = (unsigned*)(((t & 1) ? hp0 : hp1) + (size_t)bg * 8192);

    // ---- bulk h load: 64B/thread (8 x u64 agent loads, one LLC RT)
    unsigned long long hch[8];
    #pragma unroll
    for (int k = 0; k < 8; ++k)
      hch[k] = __hip_atomic_load(hq + hc * 128 + hj * 8 + k,
                                 __ATOMIC_RELAXED, __HIP_MEMORY_SCOPE_AGENT);

    // ---- stage x (16B) + h (64B) into the Z plane
    *(uint4*)((char*)&zpl[tid >> 4][0] + (tid & 15) * 16) = xv;
    #pragma unroll
    for (int k = 0; k < 8; ++k)
      *(unsigned long long*)(&zpl[hc][0] + 128 + hj * 32 + 4 * k) = hch[k];
    __syncthreads();   // (1) staging complete

    // ---- MFMA: 20 k-steps x 1 fp16 MFMA, full k=640
    f32x4 aE = {0, 0, 0, 0}, aO = {0, 0, 0, 0};
    const short* zr = &zpl[cB][0];
#define KS(s_, AF, ACC) \
  { f16x8 B = *(const f16x8*)(zr + (s_) * 32 + gch * 8); \
    ACC = __builtin_amdgcn_mfma_f32_16x16x32_f16(AF, B, ACC, 0, 0, 0); }
    KS(0, A0, aE)  KS(1, A1, aO)  KS(2, A2, aE)  KS(3, A3, aO)
    KS(4, A4, aE)  KS(5, A5, aO)  KS(6, A6, aE)  KS(7, A7, aO)
    KS(8, A8, aE)  KS(9, A9, aO)  KS(10, A10, aE) KS(11, A11, aO)
    KS(12, A12, aE) KS(13, A13, aO) KS(14, A14, aE) KS(15, A15, aO)
    KS(16, A16, aE) KS(17, A17, aO) KS(18, A18, aE) KS(19, A19, aO)
#undef KS

    // ---- in-lane cell update: acc[r] = gate r of (hu, cb)
    float s0 = aE[0] + aO[0] + bsq[0];
    float s1 = aE[1] + aO[1] + bsq[1];
    float s2 = aE[2] + aO[2] + bsq[2];
    float s3 = aE[3] + aO[3] + bsq[3];
    float iv = fsigmoid(s0);
    float fv = fsigmoid(s1);
    float gv = ftanh(s2);
    float ov = fsigmoid(s3);
    c_reg = fv * c_reg + iv * gv;
    float h2 = ov * ftanh(c_reg);

    // ---- pack fp16 pair across u_loc partner lanes, agent store u32
    unsigned hb = f16b(h2);
    unsigned other = __shfl_xor(hb, 16);
    if (((l >> 4) & 1) == 0)
      __hip_atomic_store(hdw + cb * 256 + (hu >> 1), hb | (other << 16),
                         __ATOMIC_RELAXED, __HIP_MEMORY_SCOPE_AGENT);
    if (t == mylen - 1) out[(size_t)gb * HID + hu] = h2;

    __syncthreads();   // (2) per-wave vmcnt drain -> all h stores durable
    if (tid == 0)
      __hip_atomic_store((unsigned*)(flags + bg * 32 + ug), (unsigned)(t + 1),
                         __ATOMIC_RELAXED, __HIP_MEMORY_SCOPE_AGENT);
  }
}

// ---------------- launch ----------------
extern "C" void kernel_launch(void* const* d_in, const int* in_sizes, int n_in,
                              void* d_out, int out_size, void* d_ws, size_t ws_size,
                              hipStream_t stream)
{
  const float* inputs = (const float*)d_in[0];
  const int*   len    = (const int*)  d_in[1];
  const float* h0     = (const float*)d_in[2];
  const float* c0     = (const float*)d_in[3];
  const float* Wih    = (const float*)d_in[4];
  const float* Whh    = (const float*)d_in[5];
  const float* bih    = (const float*)d_in[6];
  const float* bhh    = (const float*)d_in[7];
  float* out = (float*)d_out;

  char* p = (char*)d_ws;
  unsigned short* xp = (unsigned short*)p; p += (size_t)T_STEPS * 8 * 2048 * 2;      // 32 MB
  unsigned short* wf = (unsigned short*)p; p += (size_t)2560 * 64 * 8 * 2;           // 2.6 MB
  unsigned short* hp0 = (unsigned short*)p; p += (size_t)8 * 8192 * 2;               // 128 KB
  unsigned short* hp1 = (unsigned short*)p; p += (size_t)8 * 8192 * 2;               // 128 KB
  unsigned* flags = (unsigned*)p; p += 256 * 4;

  k_prep_x<<<T_STEPS * 8, 256, 0, stream>>>(inputs, xp);
  k_prep_w<<<2560, 64, 0, stream>>>(Wih, Whh, wf);
  k_prep_h<<<256, 256, 0, stream>>>(h0, hp0, flags);

  void* args[] = {(void*)&xp, (void*)&wf, (void*)&bih, (void*)&bhh,
                  (void*)&hp0, (void*)&hp1, (void*)&c0, (void*)&len,
                  (void*)&out, (void*)&flags};
  (void)hipLaunchCooperativeKernel((void*)k_persist, dim3(NBLK), dim3(NTHR),
                                   args, 0, stream);
}